// Round 2
// baseline (178.757 us; speedup 1.0000x reference)
//
#include <hip/hip_runtime.h>

#define N_USERS 200000
#define N_ITEMS 100000
#define N_NODES 300000
#define N_EDGES 4800000
#define EMB 64
#define BATCH 4096
#define NSLOTS (2 * BATCH)
#define CAP 64          // bucket capacity; Poisson(16) overflow P ~ 1e-18

typedef unsigned int u32;

// ---------------------------------------------------------------------------
// K1 (k_map): 8192 threads. Zero slot_count AND write node2slot[node] = slot.
// Plain racy store among duplicate ids: any winner is a valid canonical slot,
// and the value is stable at the kernel boundary. No workspace clear needed:
// correctness does not depend on node2slot's initial contents (see k_filter).
// ---------------------------------------------------------------------------
__global__ void k_map(const int* __restrict__ user_id, const int* __restrict__ item_id,
                      int* __restrict__ node2slot, u32* __restrict__ slot_count) {
    int b = blockIdx.x * blockDim.x + threadIdx.x;
    if (b >= NSLOTS) return;
    slot_count[b] = 0u;
    int node = (b < BATCH) ? user_id[b] : (N_USERS + item_id[b - BATCH]);
    node2slot[node] = b;
}

// ---------------------------------------------------------------------------
// K2 (k_filter): stream adj_row (int4 = 16B/lane). Membership test is a
// single node2slot load + verify-by-backpointer:
//   s in [0,NSLOTS) AND ids[s] == r   <=>   r is a selected node.
// Garbage/stale node2slot values can never pass the verify (ids[s] is always
// a selected node), so NO workspace init pass is required at all.
// Hits: spread int atomic on slot_count (8192 addrs, L2-hot) + 4B edge-id
// scatter. No f32 atomics anywhere.
// ---------------------------------------------------------------------------
__global__ void k_filter(const int4* __restrict__ adj_row4,
                         const int* __restrict__ node2slot,
                         const int* __restrict__ user_id, const int* __restrict__ item_id,
                         u32* __restrict__ slot_count, u32* __restrict__ slot_edges) {
    u32 i = blockIdx.x * blockDim.x + threadIdx.x;
    if (i >= N_EDGES / 4) return;
    int4 rr = adj_row4[i];
    u32 e0 = i * 4u;
    #pragma unroll
    for (int k = 0; k < 4; k++) {
        int r = (&rr.x)[k];
        int s = node2slot[r];                     // 1.2MB table, L2-resident
        if ((u32)s < (u32)NSLOTS) {
            int node_s = (s < BATCH) ? user_id[s] : (N_USERS + item_id[s - BATCH]);
            if (node_s == r) {                    // verify: poison-proof
                u32 p = atomicAdd(&slot_count[s], 1u);
                if (p < CAP) slot_edges[(u32)s * CAP + p] = e0 + (u32)k;
            }
        }
    }
}

// ---------------------------------------------------------------------------
// K3 (k_accum): one wave per slot. EVERY slot (including duplicate ids)
// resolves its node's canonical slot and computes the final row from the
// canonical edge list — eliminates the separate dup-copy pass (~126 waves
// redo ~16 FMAs; free). Parallel (col,val) gather by lanes j<cnt,
// shfl-broadcast, coalesced 256B emb-row loads, register accumulate,
// write FINAL value 2*x0+acc directly (slots == output rows).
// ---------------------------------------------------------------------------
__global__ void k_accum(const u32* __restrict__ slot_count, const u32* __restrict__ slot_edges,
                        const int* __restrict__ adj_col, const float* __restrict__ vals,
                        const float* __restrict__ user_emb, const float* __restrict__ item_emb,
                        const int* __restrict__ user_id, const int* __restrict__ item_id,
                        const int* __restrict__ node2slot, float* __restrict__ out) {
    int lane = threadIdx.x & 63;
    u32 o = (u32)(blockIdx.x * blockDim.x + threadIdx.x) >> 6;
    if (o >= NSLOTS) return;
    int node = (o < BATCH) ? user_id[o] : (N_USERS + item_id[o - BATCH]);
    int cs = node2slot[node];                     // canonical slot (valid: set by k_map)
    u32 cnt = slot_count[cs];
    if (cnt > CAP) cnt = CAP;
    int c = 0; float v = 0.f;
    if ((u32)lane < cnt) {
        u32 e = slot_edges[(u32)cs * CAP + (u32)lane];  // coalesced
        c = adj_col[e];                                 // parallel gather
        v = vals[e];                                    // parallel gather
    }
    float a0 = 0.f, a1 = 0.f;
    u32 j = 0;
    for (; j + 2 <= cnt; j += 2) {                // 2-way for load ILP
        int c0 = __shfl(c, (int)j);     float v0 = __shfl(v, (int)j);
        int c1 = __shfl(c, (int)j + 1); float v1 = __shfl(v, (int)j + 1);
        const float* x0p = (c0 < N_USERS) ? user_emb + (size_t)c0 * EMB
                                          : item_emb + (size_t)(c0 - N_USERS) * EMB;
        const float* x1p = (c1 < N_USERS) ? user_emb + (size_t)c1 * EMB
                                          : item_emb + (size_t)(c1 - N_USERS) * EMB;
        a0 += v0 * x0p[lane];
        a1 += v1 * x1p[lane];
    }
    if (j < cnt) {
        int c0 = __shfl(c, (int)j); float v0 = __shfl(v, (int)j);
        const float* x0p = (c0 < N_USERS) ? user_emb + (size_t)c0 * EMB
                                          : item_emb + (size_t)(c0 - N_USERS) * EMB;
        a0 += v0 * x0p[lane];
    }
    const float* xr = (node < N_USERS) ? user_emb + (size_t)node * EMB
                                       : item_emb + (size_t)(node - N_USERS) * EMB;
    out[(size_t)o * EMB + lane] = 2.f * xr[lane] + (a0 + a1);
}

extern "C" void kernel_launch(void* const* d_in, const int* in_sizes, int n_in,
                              void* d_out, int out_size, void* d_ws, size_t ws_size,
                              hipStream_t stream) {
    const float* user_emb = (const float*)d_in[0];
    const float* item_emb = (const float*)d_in[1];
    const int* adj_row = (const int*)d_in[2];
    const int* adj_col = (const int*)d_in[3];
    const float* adj_vals = (const float*)d_in[4];
    const int* user_id = (const int*)d_in[5];
    const int* item_id = (const int*)d_in[6];
    float* out = (float*)d_out;

    // ws layout (256B aligned): node2slot 1.2MB | slot_count 32KB | slot_edges 2MB
    char* ws = (char*)d_ws;
    size_t off = 0;
    int* node2slot = (int*)(ws + off);  off += ((size_t)N_NODES * 4 + 255) & ~(size_t)255;
    u32* slot_count= (u32*)(ws + off);  off += ((size_t)NSLOTS * 4 + 255) & ~(size_t)255;
    u32* slot_edges= (u32*)(ws + off);

    const int B = 256;
    k_map<<<(NSLOTS + B - 1) / B, B, 0, stream>>>(user_id, item_id, node2slot, slot_count);
    k_filter<<<(N_EDGES / 4 + B - 1) / B, B, 0, stream>>>((const int4*)adj_row, node2slot,
                                                          user_id, item_id,
                                                          slot_count, slot_edges);
    k_accum<<<(NSLOTS * 64 + B - 1) / B, B, 0, stream>>>(slot_count, slot_edges, adj_col,
                                                         adj_vals, user_emb, item_emb,
                                                         user_id, item_id, node2slot, out);
}